// Round 4
// baseline (186.147 us; speedup 1.0000x reference)
//
#include <hip/hip_runtime.h>
#include <math.h>

#define NPIX (512*1024)   // H*W = 524288
#define NB   8
#define NACC 68           // 64 p_cl + 4 p_l  (p_c derived as row-sums of p_cl)
#define BLOCKS 1024
#define TPB 256
#define NWAVES (TPB/64)
#define HROWS 21          // rows 0..19: k' = k+2 (window k in [-2,17]); row 20 unused spare
#define HCOLS 6           // c' = c+1 (c in [-1,4])
#define HSTRIDE 128       // per-wave LDS region (>= 21*6=126), padded

__device__ __forceinline__ float fexp2(float x){ return __builtin_amdgcn_exp2f(x); }
__device__ __forceinline__ float frcp (float x){ return __builtin_amdgcn_rcpf(x); }

// One pixel: windowed camera histogram (3 live sigmoids -> 4-bin Pc window),
// label soft-argmax (beta=500) -> single live edge -> 2 weights.
// p_cl outer product (4x2 nonzeros) goes to the per-wave LDS histogram via
// ds_add_f32; p_l accumulates in registers (avoids a hot LDS row).
__device__ __forceinline__ void pxAccum(float gsum, float x0, float x1, float x2, float x3,
                                        float* __restrict__ wh, float (&pl)[4])
{
    constexpr float L2E  = 1.4426950408889634f;
    constexpr float ESTP = 12.5f * L2E;    // camera edge scale, exp2 domain
    constexpr float BSC  = 500.0f * L2E;   // softmax beta
    constexpr float LSC  = 1000.0f * L2E;  // label edge scale

    // ---- camera: u = 16*gray, live edges jr-1, jr, jr+1 ----
    float u   = gsum * (16.0f / 3.0f);
    float jr  = rintf(u);
    float d   = u - jr;                    // in [-0.5, 0.5]
    float sm1 = frcp(1.0f + fexp2(-ESTP * (d + 1.0f)));  // sigma_{jr-1}
    float s0  = frcp(1.0f + fexp2(-ESTP * d));           // sigma_{jr}
    float sp1 = frcp(1.0f + fexp2(-ESTP * (d - 1.0f)));  // sigma_{jr+1}
    float P0  = 1.0f - sm1;   // bin k = jr-2  (row k' = jr+0)
    float P1  = sm1 - s0;     // bin k = jr-1  (row k' = jr+1)
    float P2  = s0 - sp1;     // bin k = jr    (row k' = jr+2)
    float P3  = sp1;          // bin k = jr+1  (row k' = jr+3)

    // ---- label: soft-argmax then single live edge sigmoid ----
    float m  = fmaxf(fmaxf(x0, x1), fmaxf(x2, x3));
    float mk = m * BSC;
    float e0 = fexp2(fmaf(x0, BSC, -mk));
    float e1 = fexp2(fmaf(x1, BSC, -mk));
    float e2 = fexp2(fmaf(x2, BSC, -mk));
    float e3 = fexp2(fmaf(x3, BSC, -mk));
    float am = fmaf(3.0f, e3, fmaf(2.0f, e2, e1)) * frcp(e0 + e1 + e2 + e3 + 1e-12f);

    float fj = rintf(am + 0.5f);                            // nearest edge index (0..4)
    float v  = frcp(1.0f + fexp2((fj - 0.5f - am) * LSC));  // sigma at that edge
    float w0 = 1.0f - v;   // label bin c = fj-1  -> col c' = fj
    float w1 = v;          // label bin c = fj    -> col c' = fj+1

    // p_l in registers (static-indexed after unroll)
    #pragma unroll
    for (int c = 0; c < 4; c++) {
        float add = (fj == (float)(c + 1)) ? w0 : (fj == (float)c) ? w1 : 0.0f;
        pl[c] += add;
    }

    // p_cl window: rows jr..jr+3 (k' space), cols fj, fj+1
    int base = (int)jr * HCOLS + (int)fj;
    float* hb = wh + base;
    atomicAdd(hb + 0,              P0 * w0); atomicAdd(hb + 1,              P0 * w1);
    atomicAdd(hb + HCOLS,          P1 * w0); atomicAdd(hb + HCOLS + 1,      P1 * w1);
    atomicAdd(hb + 2 * HCOLS,      P2 * w0); atomicAdd(hb + 2 * HCOLS + 1,  P2 * w1);
    atomicAdd(hb + 3 * HCOLS,      P3 * w0); atomicAdd(hb + 3 * HCOLS + 1,  P3 * w1);
}

__launch_bounds__(TPB, 2)
__global__ void nid_partial(const float* __restrict__ cam,
                            const float* __restrict__ lab,
                            float* __restrict__ ws)
{
    __shared__ float hist[NWAVES * HSTRIDE];
    __shared__ float plred[NWAVES][4];

    const int tid = blockIdx.x * TPB + threadIdx.x;   // 262144 threads
    const int n0  = tid * 2;                          // pixel pair (n0, n0+1)
    const int lane = threadIdx.x & 63;
    const int wv   = threadIdx.x >> 6;
    float* wh = hist + wv * HSTRIDE;

    #pragma unroll
    for (int i = threadIdx.x; i < NWAVES * HSTRIDE; i += TPB) hist[i] = 0.0f;
    __syncthreads();

    float pl[4] = {0.f, 0.f, 0.f, 0.f};   // p_l partial, both pixels

    #pragma unroll
    for (int b = 0; b < NB; b++) {
        const float* cbase = cam + (size_t)(b * 3) * NPIX + n0;
        float2 c0 = *(const float2*)(cbase);
        float2 c1 = *(const float2*)(cbase + NPIX);
        float2 c2 = *(const float2*)(cbase + 2 * NPIX);
        const float* lbase = lab + (size_t)(b * 4) * NPIX + n0;
        float2 a0 = *(const float2*)(lbase);
        float2 a1 = *(const float2*)(lbase + NPIX);
        float2 a2 = *(const float2*)(lbase + 2 * NPIX);
        float2 a3 = *(const float2*)(lbase + 3 * NPIX);

        pxAccum(c0.x + c1.x + c2.x, a0.x, a1.x, a2.x, a3.x, wh, pl);
        pxAccum(c0.y + c1.y + c2.y, a0.y, a1.y, a2.y, a3.y, wh, pl);
    }

    // wave-reduce p_l (4 values) and stage per wave
    #pragma unroll
    for (int c = 0; c < 4; c++) {
        float s = pl[c];
        s += __shfl_xor(s, 1);
        s += __shfl_xor(s, 2);
        s += __shfl_xor(s, 4);
        s += __shfl_xor(s, 8);
        s += __shfl_xor(s, 16);
        s += __shfl_xor(s, 32);
        if (lane == 0) plred[wv][c] = s;
    }

    __syncthreads();
    if (threadIdx.x < NACC) {
        int t = threadIdx.x;
        float s;
        if (t < 64) {
            int idx = ((t >> 2) + 2) * HCOLS + (t & 3) + 1;  // k'=k+2, c'=c+1
            s = hist[idx] + hist[HSTRIDE + idx] + hist[2 * HSTRIDE + idx] + hist[3 * HSTRIDE + idx];
        } else {
            int c = t - 64;
            s = plred[0][c] + plred[1][c] + plred[2][c] + plred[3][c];
        }
        ws[(size_t)blockIdx.x * NACC + t] = s;
    }
}

// Kernel 2: reduce 1024 block-partials in double, compute NID scalar.
__global__ void nid_final(const float* __restrict__ ws, float* __restrict__ out)
{
    __shared__ double partA[8][NACC];
    __shared__ double sm[NACC];
    __shared__ double tots[2];
    const int t = threadIdx.x;  // block of 544

    if (t < 8 * NACC) {
        int v = t % NACC;
        int g = t / NACC;
        double s = 0.0;
        #pragma unroll 8
        for (int i = g * 128; i < g * 128 + 128; i++)
            s += (double)ws[(size_t)i * NACC + v];
        partA[g][v] = s;
    }
    __syncthreads();
    if (t < NACC) {
        double s = 0.0;
        #pragma unroll
        for (int g = 0; g < 8; g++) s += partA[g][t];
        sm[t] = s;
    }
    __syncthreads();
    if (t == 0) {
        double a = 0, bb = 0;
        for (int v = 0; v < 64; v++) a += sm[v];
        for (int c = 0; c < 4; c++)  bb += sm[64 + c];
        tots[0] = a; tots[1] = bb;
    }
    __syncthreads();
    if (t < 64) {
        int k = t >> 2, c = t & 3;
        double pcl = sm[t] / tots[0];
        double pc  = (sm[k * 4] + sm[k * 4 + 1] + sm[k * 4 + 2] + sm[k * 4 + 3]) / tots[0];
        double pll = sm[64 + c] / tots[1];
        double lp  = log(pcl + 1e-7);
        double lo  = log(pc * pll + 1e-7);
        double dI  = pcl * (lp - lo);
        double dH  = -pcl * lp;
        #pragma unroll
        for (int mm = 1; mm < 64; mm <<= 1) {
            dI += __shfl_xor(dI, mm);
            dH += __shfl_xor(dH, mm);
        }
        if (t == 0) out[0] = (float)((1.0 - dI / dH - 0.95) * 20.0);
    }
}

extern "C" void kernel_launch(void* const* d_in, const int* in_sizes, int n_in,
                              void* d_out, int out_size, void* d_ws, size_t ws_size,
                              hipStream_t stream)
{
    const float* cam = (const float*)d_in[0];
    const float* lab = (const float*)d_in[1];
    float* ws = (float*)d_ws;

    hipLaunchKernelGGL(nid_partial, dim3(BLOCKS), dim3(TPB), 0, stream, cam, lab, ws);
    hipLaunchKernelGGL(nid_final, dim3(1), dim3(544), 0, stream, ws, (float*)d_out);
}

// Round 5
// 52.452 us; speedup vs baseline: 3.5489x; 3.5489x over previous
//
#include <hip/hip_runtime.h>
#include <math.h>

#define NPIX (512*1024)   // H*W = 524288
#define NB   8
#define KBINS 16
#define CBINS 4
#define NACC 68           // 64 p_cl + 4 p_l  (p_c derived as row-sums of p_cl)
#define BLOCKS 512        // 512 blocks x 256 thr x 4 px = NPIX
#define TPB 256

__device__ __forceinline__ float fexp2(float x){ return __builtin_amdgcn_exp2f(x); }
__device__ __forceinline__ float frcp (float x){ return __builtin_amdgcn_rcpf(x); }

// One batch's 7 float4 loads (3 camera planes + 4 label planes) for 4 pixels.
struct B7 { float4 c0, c1, c2, l0, l1, l2, l3; };

__device__ __forceinline__ B7 loadB(const float* __restrict__ cam,
                                    const float* __restrict__ lab,
                                    int n0, int b)
{
    B7 r;
    const float* cb = cam + (size_t)(b * 3) * NPIX + n0;
    r.c0 = *(const float4*)(cb);
    r.c1 = *(const float4*)(cb + NPIX);
    r.c2 = *(const float4*)(cb + 2 * NPIX);
    const float* lb = lab + (size_t)(b * 4) * NPIX + n0;
    r.l0 = *(const float4*)(lb);
    r.l1 = *(const float4*)(lb + NPIX);
    r.l2 = *(const float4*)(lb + 2 * NPIX);
    r.l3 = *(const float4*)(lb + 3 * NPIX);
    return r;
}

// One pixel, one batch: 17 camera edge sigmoids into Sc, label soft-argmax
// (beta=500) + single live edge sigmoid into pl. All static indexing.
__device__ __forceinline__ void px1(float gsum, float x0, float x1, float x2, float x3,
                                    float (&Sc)[KBINS + 1], float (&pl)[CBINS])
{
    constexpr float L2E  = 1.4426950408889634f;
    constexpr float CSC  = 200.0f / 3.0f * L2E;
    constexpr float ESTP = 12.5f * L2E;
    constexpr float BSC  = 500.0f * L2E;
    constexpr float LSC  = 1000.0f * L2E;

    float t = gsum * CSC;
    #pragma unroll
    for (int j = 0; j <= KBINS; j++)
        Sc[j] += frcp(1.0f + fexp2((float)j * ESTP - t));

    float m  = fmaxf(fmaxf(x0, x1), fmaxf(x2, x3));
    float mk = m * BSC;
    float e0 = fexp2(fmaf(x0, BSC, -mk));
    float e1 = fexp2(fmaf(x1, BSC, -mk));
    float e2 = fexp2(fmaf(x2, BSC, -mk));
    float e3 = fexp2(fmaf(x3, BSC, -mk));
    float am = fmaf(3.0f, e3, fmaf(2.0f, e2, e1)) * frcp(e0 + e1 + e2 + e3 + 1e-12f);

    // label edges at j-0.5, scale 1000: only nearest edge non-saturated in fp32
    float fj = rintf(am + 0.5f);
    float v  = frcp(1.0f + fexp2((fj - 0.5f - am) * LSC));
    #pragma unroll
    for (int c = 0; c < CBINS; c++) {
        float add = (fj == (float)(c + 1)) ? (1.0f - v)
                  : (fj == (float)c)       ? v : 0.0f;
        pl[c] += add;
    }
}

// Kernel 1: 4 consecutive pixels/thread (float4), explicit 1-deep software
// pipeline over the 8 batches: batch b+1's loads issue before batch b's
// transcendental block. launch_bounds(256,2) -> 256-VGPR budget so the
// prefetch registers actually fit (the 128-cap build refused to prefetch).
__launch_bounds__(TPB, 2)
__global__ void nid_partial(const float* __restrict__ cam,
                            const float* __restrict__ lab,
                            float* __restrict__ ws)
{
    const int tid = blockIdx.x * TPB + threadIdx.x;   // 131072 threads
    const int n0  = tid * 4;                          // pixels n0..n0+3

    float Sc0[KBINS + 1], Sc1[KBINS + 1], Sc2[KBINS + 1], Sc3[KBINS + 1];
    float pl0[CBINS], pl1[CBINS], pl2[CBINS], pl3[CBINS];
    #pragma unroll
    for (int j = 0; j <= KBINS; j++) { Sc0[j] = 0.f; Sc1[j] = 0.f; Sc2[j] = 0.f; Sc3[j] = 0.f; }
    #pragma unroll
    for (int c = 0; c < CBINS; c++) { pl0[c] = 0.f; pl1[c] = 0.f; pl2[c] = 0.f; pl3[c] = 0.f; }

    B7 cur = loadB(cam, lab, n0, 0);
    #pragma unroll
    for (int b = 0; b < NB; b++) {
        B7 nxt;
        if (b + 1 < NB) nxt = loadB(cam, lab, n0, b + 1);   // prefetch next batch

        px1(cur.c0.x + cur.c1.x + cur.c2.x, cur.l0.x, cur.l1.x, cur.l2.x, cur.l3.x, Sc0, pl0);
        px1(cur.c0.y + cur.c1.y + cur.c2.y, cur.l0.y, cur.l1.y, cur.l2.y, cur.l3.y, Sc1, pl1);
        px1(cur.c0.z + cur.c1.z + cur.c2.z, cur.l0.z, cur.l1.z, cur.l2.z, cur.l3.z, Sc2, pl2);
        px1(cur.c0.w + cur.c1.w + cur.c2.w, cur.l0.w, cur.l1.w, cur.l2.w, cur.l3.w, Sc3, pl3);

        if (b + 1 < NB) cur = nxt;
    }

    // ---- per-thread outer products (batch-summed edges -> Pc -> p_cl) ----
    float acc[NACC];
    #pragma unroll
    for (int i = 0; i < NACC; i++) acc[i] = 0.f;
    #pragma unroll
    for (int k = 0; k < KBINS; k++) {
        float Pc0 = Sc0[k] - Sc0[k + 1];
        float Pc1 = Sc1[k] - Sc1[k + 1];
        float Pc2 = Sc2[k] - Sc2[k + 1];
        float Pc3 = Sc3[k] - Sc3[k + 1];
        #pragma unroll
        for (int c = 0; c < CBINS; c++)
            acc[k * 4 + c] = fmaf(Pc0, pl0[c], fmaf(Pc1, pl1[c], fmaf(Pc2, pl2[c], Pc3 * pl3[c])));
    }
    #pragma unroll
    for (int c = 0; c < CBINS; c++) acc[64 + c] = pl0[c] + pl1[c] + pl2[c] + pl3[c];

    // ---- block reduction: 3-step butterfly (8-lane sums) -> LDS -> 68 threads ----
    __shared__ float red[32][NACC];
    const int lane = threadIdx.x & 63;
    const int wv   = threadIdx.x >> 6;

    #pragma unroll
    for (int i = 0; i < NACC; i++) {
        float v = acc[i];
        v += __shfl_xor(v, 1);
        v += __shfl_xor(v, 2);
        v += __shfl_xor(v, 4);
        if ((lane & 7) == 0) red[wv * 8 + (lane >> 3)][i] = v;
    }

    __syncthreads();
    if (threadIdx.x < NACC) {
        float s = 0.f;
        #pragma unroll
        for (int g = 0; g < 32; g++) s += red[g][threadIdx.x];
        ws[(size_t)blockIdx.x * NACC + threadIdx.x] = s;
    }
}

// Kernel 2: reduce 512 block-partials in double, compute NID scalar.
__global__ void nid_final(const float* __restrict__ ws, float* __restrict__ out)
{
    __shared__ double partA[8][NACC];
    __shared__ double sm[NACC];
    __shared__ double tots[2];
    const int t = threadIdx.x;  // block of 544

    if (t < 8 * NACC) {
        int v = t % NACC;
        int g = t / NACC;
        double s = 0.0;
        #pragma unroll 8
        for (int i = g * 64; i < g * 64 + 64; i++)
            s += (double)ws[(size_t)i * NACC + v];
        partA[g][v] = s;
    }
    __syncthreads();
    if (t < NACC) {
        double s = 0.0;
        #pragma unroll
        for (int g = 0; g < 8; g++) s += partA[g][t];
        sm[t] = s;
    }
    __syncthreads();
    if (t == 0) {
        double a = 0, bb = 0;
        for (int v = 0; v < 64; v++) a += sm[v];
        for (int c = 0; c < 4; c++)  bb += sm[64 + c];
        tots[0] = a; tots[1] = bb;
    }
    __syncthreads();
    if (t < 64) {
        int k = t >> 2, c = t & 3;
        double pcl = sm[t] / tots[0];
        double pc  = (sm[k * 4] + sm[k * 4 + 1] + sm[k * 4 + 2] + sm[k * 4 + 3]) / tots[0];
        double pll = sm[64 + c] / tots[1];
        double lp  = log(pcl + 1e-7);
        double lo  = log(pc * pll + 1e-7);
        double dI  = pcl * (lp - lo);
        double dH  = -pcl * lp;
        #pragma unroll
        for (int mm = 1; mm < 64; mm <<= 1) {
            dI += __shfl_xor(dI, mm);
            dH += __shfl_xor(dH, mm);
        }
        if (t == 0) out[0] = (float)((1.0 - dI / dH - 0.95) * 20.0);
    }
}

extern "C" void kernel_launch(void* const* d_in, const int* in_sizes, int n_in,
                              void* d_out, int out_size, void* d_ws, size_t ws_size,
                              hipStream_t stream)
{
    const float* cam = (const float*)d_in[0];
    const float* lab = (const float*)d_in[1];
    float* ws = (float*)d_ws;

    hipLaunchKernelGGL(nid_partial, dim3(BLOCKS), dim3(TPB), 0, stream, cam, lab, ws);
    hipLaunchKernelGGL(nid_final, dim3(1), dim3(544), 0, stream, ws, (float*)d_out);
}